// Round 7
// baseline (263.246 us; speedup 1.0000x reference)
//
#include <hip/hip_runtime.h>
#include <math.h>

// TaskAdaptiveRouter: logits = x @ Wr[:, :2048]^T + task_logits; softmax; top2; aux.
// B=4, L=4096 -> 16384 tokens; D=2048; DT=16; E=64; K=2; TEMP=1.
//
// d_out (f32): [0,32768) topw ; [32768,65536) topi(float) ; [65536,1114112) probs ;
//              [1114112] aux.
// d_ws  (f32): [0,256) task logits tl[4][64] ; [256,1280) P/F slots [8][{P:64,F:64}].
//
// k2: grid 256 x 576thr (8 consumer waves + 1 producer wave). Three latency classes,
// three disjoint mechanisms (vmcnt is per-wave and in-order, so never mix streams).
// R6 fix: every raw s_barrier is now BAR() = s_barrier + ""::"memory" + sched_barrier(0).
// The bare s_barrier intrinsic has NO memory semantics in the compiler model, so LDS
// reads/writes could be scheduled across it (intermittent replay divergence in R5).

#define DDIM 2048
#define WROW 2064          // W_router row stride (floats)

typedef unsigned int u32;
typedef const __attribute__((address_space(1))) u32* gp1;
typedef __attribute__((address_space(3))) u32* lp3;
using f32x4 = __attribute__((ext_vector_type(4))) float;

// barrier with compiler-level memory fence + scheduler pin (no extra runtime cost)
#define BAR() do {                                                              \
        __builtin_amdgcn_s_barrier();                                           \
        asm volatile("" ::: "memory");                                          \
        __builtin_amdgcn_sched_barrier(0);                                      \
    } while (0)

// ---------------- kernel 1: task proj + task logits + zero P/F slots -------------
__global__ void k1_task(const float* __restrict__ z, const float* __restrict__ Wp,
                        const float* __restrict__ bp, const float* __restrict__ Wr,
                        const float* __restrict__ eb, float* __restrict__ wsb) {
    __shared__ float tp[4][16];
    const int t = threadIdx.x;
    if (t < 64) {
        const int b = t >> 4, r = t & 15;
        float s = bp[r];
        #pragma unroll
        for (int i = 0; i < 16; ++i) s += z[b * 16 + i] * Wp[r * 16 + i];
        tp[b][r] = 0.5f * s * (1.0f + erff(s * 0.70710678118654752440f));
    }
    #pragma unroll
    for (int i = t; i < 1024; i += 256) wsb[256 + i] = 0.0f;   // zero 8 P/F slots
    __syncthreads();
    {
        const int b = t >> 6, e = t & 63;
        const float* wr = Wr + (size_t)e * WROW + DDIM;
        float s = eb[e];
        #pragma unroll
        for (int i = 0; i < 16; ++i) s += tp[b][i] * wr[i];
        wsb[b * 64 + e] = s;
    }
}

// ---------------- kernel 2: fused logits + softmax + top2 + probs + P/f ----------
__global__ __launch_bounds__(576, 1) void k2_fused(const float* __restrict__ x,
                                                   const float* __restrict__ Wr,
                                                   float* __restrict__ wsb,
                                                   float* __restrict__ out) {
    __shared__ __align__(16) float xbuf[3 * 2048];   // triple-buffered x tiles (24 KB)
    __shared__ __align__(16) float lg[64 * 68];      // logit exchange (17 KB)
    __shared__ __align__(16) float pf[8 * 128];      // P/f partials (4 KB)

    const int tid  = threadIdx.x;
    const int wv   = __builtin_amdgcn_readfirstlane(tid >> 6);  // uniform wave id
    const int lane = tid & 63;
    const int tok0 = blockIdx.x * 64;
    const int bb   = tok0 >> 12;            // batch index (uniform)

    if (wv == 8) {
        // ---------------- producer: x DMA staging; vmcnt = DMAs only ---------------
        const float* xrow = x + (size_t)(tok0 + lane) * DDIM;   // lane = token
#define STAGEALL(t) do {                                                        \
            float* _d = &xbuf[((t) % 3) * 2048];                                \
            const float* _s = xrow + (t) * 32;                                  \
            _Pragma("unroll")                                                   \
            for (int s = 0; s < 8; ++s)                                         \
                __builtin_amdgcn_global_load_lds((gp1)(_s + s * 4),             \
                                                 (lp3)(_d + s * 256), 16, 0, 0);\
        } while (0)
        STAGEALL(0); STAGEALL(1);
        asm volatile("s_waitcnt vmcnt(8)" ::: "memory");   // tile 0 landed
        BAR();
        for (int t = 0; t < 64; ++t) {
            if (t < 62) {
                STAGEALL(t + 2);
                asm volatile("s_waitcnt vmcnt(8)" ::: "memory");  // tile t+1 landed
            } else {
                asm volatile("s_waitcnt vmcnt(0)" ::: "memory");
            }
            BAR();
        }
#undef STAGEALL
    } else {
        // ---------------- consumer: FMAs; vmcnt = W-loads only ---------------------
        const int e0 = wv * 8;
        float acc[8];
        #pragma unroll
        for (int e = 0; e < 8; ++e) acc[e] = wsb[bb * 64 + e0 + e];  // task logits
        // force the acc loads' compiler vmcnt wait to land BEFORE any WLOAD
        #pragma unroll
        for (int e = 0; e < 8; ++e) asm volatile("" : "+v"(acc[e]));
        __builtin_amdgcn_sched_barrier(0);

        int vz = 0;
        const float* wr0 = Wr + (size_t)e0 * WROW;    // uniform (wv uniform)
        f32x4 wA[8], wB[8], wC[8], wD[8];

#define WLOAD(W, koff) do {                                                     \
            _Pragma("unroll")                                                   \
            for (int e = 0; e < 8; ++e)                                         \
                asm volatile("global_load_dwordx4 %0, %1, %2"                   \
                    : "=&v"(W[e])                                               \
                    : "v"(vz), "s"(wr0 + (size_t)e * WROW + (koff)));           \
        } while (0)

#define VMWAIT24(W)                                                             \
            asm volatile("s_waitcnt vmcnt(24)"                                  \
                : "+v"(W[0]), "+v"(W[1]), "+v"(W[2]), "+v"(W[3]),               \
                  "+v"(W[4]), "+v"(W[5]), "+v"(W[6]), "+v"(W[7]))

#define FMA8(xv, W) do {                                                        \
            _Pragma("unroll")                                                   \
            for (int e = 0; e < 8; ++e) {                                       \
                acc[e] += xv.x * W[e].x; acc[e] += xv.y * W[e].y;               \
                acc[e] += xv.z * W[e].z; acc[e] += xv.w * W[e].w;               \
            }                                                                   \
        } while (0)

        // SUB(s): wait W batch for subtile s, FMA, prefetch subtile s+4 (same buf).
        // koff = kb + 16 + 4s; at t=63 max = 2060 -> floats 2060..2063 of the row:
        // in-bounds (row len 2064), unused.
#define SUB(s, W) do {                                                          \
            VMWAIT24(W);                                                        \
            const float4 xv = *(const float4*)(bufc + (s) * 256 + (lane << 2)); \
            FMA8(xv, W);                                                        \
            WLOAD(W, kb + 16 + 4 * (s));                                        \
        } while (0)

        WLOAD(wA, 0); WLOAD(wB, 4); WLOAD(wC, 8); WLOAD(wD, 12);
        BAR();                                        // tile 0 ready
        for (int t = 0; t < 64; ++t) {
            const float* bufc = &xbuf[(t % 3) * 2048];
            const int kb = t * 32;
            SUB(0, wA); SUB(1, wB); SUB(2, wC); SUB(3, wD);
            SUB(4, wA); SUB(5, wB); SUB(6, wC); SUB(7, wD);
            // drain DS only (vmcnt untouched) before signaling buffer reusable
            asm volatile("s_waitcnt lgkmcnt(0)" ::: "memory");
            BAR();
        }
        // drain dangling W prefetches: in-flight asm loads must not land in
        // VGPRs the allocator has reused for the epilogue
        asm volatile("s_waitcnt vmcnt(0)"
            : "+v"(wA[0]), "+v"(wA[1]), "+v"(wA[2]), "+v"(wA[3]),
              "+v"(wA[4]), "+v"(wA[5]), "+v"(wA[6]), "+v"(wA[7]),
              "+v"(wB[0]), "+v"(wB[1]), "+v"(wB[2]), "+v"(wB[3]),
              "+v"(wB[4]), "+v"(wB[5]), "+v"(wB[6]), "+v"(wB[7]));
        asm volatile("s_waitcnt vmcnt(0)"
            : "+v"(wC[0]), "+v"(wC[1]), "+v"(wC[2]), "+v"(wC[3]),
              "+v"(wC[4]), "+v"(wC[5]), "+v"(wC[6]), "+v"(wC[7]),
              "+v"(wD[0]), "+v"(wD[1]), "+v"(wD[2]), "+v"(wD[3]),
              "+v"(wD[4]), "+v"(wD[5]), "+v"(wD[6]), "+v"(wD[7]));
        __builtin_amdgcn_sched_barrier(0);
#undef WLOAD
#undef VMWAIT24
#undef FMA8
#undef SUB

        // ---- logit exchange: lane=token writes its 8 experts ----
        #pragma unroll
        for (int e = 0; e < 8; e += 4) {
            float4 v;
            v.x = acc[e]; v.y = acc[e + 1]; v.z = acc[e + 2]; v.w = acc[e + 3];
            *(float4*)&lg[lane * 68 + e0 + e] = v;
        }
    }

    __syncthreads();

    // ---- softmax/top2 for tokens 8wv..8wv+7 ; lane = expert (consumers only) ----
    if (wv < 8) {
        float pacc = 0.0f, facc = 0.0f;
        for (int i = 0; i < 8; ++i) {
            const int tk = wv * 8 + i;
            const float v = lg[tk * 68 + lane];
            float m1 = v; int i1 = lane;
            #pragma unroll
            for (int off = 32; off; off >>= 1) {
                const float ov = __shfl_xor(m1, off, 64);
                const int   oi = __shfl_xor(i1, off, 64);
                if (ov > m1 || (ov == m1 && oi < i1)) { m1 = ov; i1 = oi; }
            }
            const float vx = (lane == i1) ? -3.4e38f : v;
            float m2 = vx; int i2 = lane;
            #pragma unroll
            for (int off = 32; off; off >>= 1) {
                const float ov = __shfl_xor(m2, off, 64);
                const int   oi = __shfl_xor(i2, off, 64);
                if (ov > m2 || (ov == m2 && oi < i2)) { m2 = ov; i2 = oi; }
            }
            const float p = __expf(v - m1);
            float s = p;
            #pragma unroll
            for (int off = 32; off; off >>= 1) s += __shfl_xor(s, off, 64);
            const float rZ = 1.0f / s;
            const float pn = p * rZ;
            const int   T  = tok0 + tk;
            out[65536 + (size_t)T * 64 + lane] = pn;      // coalesced 256 B
            pacc += pn;
            facc += (lane == i1 ? 1.0f : 0.0f) + (lane == i2 ? 1.0f : 0.0f);
            if (lane == 0) {
                const float q1 = rZ, q2 = __expf(m2 - m1) * rZ;
                const float dn = 1.0f / (q1 + q2 + 1e-8f);
                float2 tw; tw.x = q1 * dn; tw.y = q2 * dn;
                *(float2*)(out + (size_t)T * 2) = tw;
                float2 ti; ti.x = (float)i1; ti.y = (float)i2;
                *(float2*)(out + 32768 + (size_t)T * 2) = ti;
            }
        }
        pf[wv * 128 + lane]      = pacc;
        pf[wv * 128 + 64 + lane] = facc;
    }
    __syncthreads();

    // ---- block-level P/f reduce -> one atomic per address per block (8 slots) ----
    if (wv == 0) {
        float ps = 0.0f, fs = 0.0f;
        #pragma unroll
        for (int w2 = 0; w2 < 8; ++w2) {
            ps += pf[w2 * 128 + lane];
            fs += pf[w2 * 128 + 64 + lane];
        }
        const int slot = blockIdx.x & 7;
        atomicAdd(wsb + 256 + slot * 128 + lane, ps);
        atomicAdd(wsb + 256 + slot * 128 + 64 + lane, fs);
    }
}

// ---------------- kernel 3: aux loss ----------------------------------------------
__global__ void k3_aux(const float* __restrict__ wsb, float* __restrict__ out) {
    const int e = threadIdx.x;  // 64 threads
    float P = 0.0f, F = 0.0f;
    #pragma unroll
    for (int s = 0; s < 8; ++s) {
        P += wsb[256 + s * 128 + e];
        F += wsb[256 + s * 128 + 64 + e];
    }
    float val = P * F;
    #pragma unroll
    for (int off = 32; off; off >>= 1) val += __shfl_xor(val, off, 64);
    if (e == 0)
        out[1114112] = 64.0f * val / (16384.0f * 2.0f * 16384.0f);
}

extern "C" void kernel_launch(void* const* d_in, const int* in_sizes, int n_in,
                              void* d_out, int out_size, void* d_ws, size_t ws_size,
                              hipStream_t stream) {
    (void)in_sizes; (void)n_in; (void)out_size; (void)ws_size;
    const float* x  = (const float*)d_in[0];
    const float* z  = (const float*)d_in[1];
    const float* Wr = (const float*)d_in[2];
    const float* Wp = (const float*)d_in[3];
    const float* bp = (const float*)d_in[4];
    const float* eb = (const float*)d_in[5];
    float* out = (float*)d_out;
    float* wsb = (float*)d_ws;

    hipLaunchKernelGGL(k1_task,  dim3(1),   dim3(256), 0, stream, z, Wp, bp, Wr, eb, wsb);
    hipLaunchKernelGGL(k2_fused, dim3(256), dim3(576), 0, stream, x, Wr, wsb, out);
    hipLaunchKernelGGL(k3_aux,   dim3(1),   dim3(64),  0, stream, wsb, out);
}